// Round 10
// baseline (96.283 us; speedup 1.0000x reference)
//
#include <hip/hip_runtime.h>

// GraphProposalNetwork on MI355X — round 10.
// Algebra: feat=x@Wp+bp is linear into W1 and pair=[vi,vj], so
//   h1[b,i,j,:] = lrelu( cc + x_i@Ma + x_j@Mb ),  Ma=Wp@W1[0:16], Mb=Wp@W1[16:32],
//   cc = bp@W1[0:16] + bp@W1[16:32] + b1  (all fused once in a pre-kernel).
// Round-10: 1 LANE = 1 EDGE. Zero LDS, zero barriers, zero inter-lane deps.
// 25.6K independent waves (vs 5.5K), perfectly coalesced stores (lane==edge),
// ~280 packed ops/lane. Removes the per-block serial critical path (3 barriers +
// s_load waits + store drain at 1.5-3 waves/SIMD) that R7's profile exposed
// (VALUBusy 19%, occupancy 23%, all other counters clean).

typedef float v2f __attribute__((ext_vector_type(2)));
typedef float v4f __attribute__((ext_vector_type(4)));

constexpr float NEG = 0.2f;

// ws layout (floats): Ma[3][32] @0, Mb[3][32] @96, cc[32] @192  (224 total)
__global__ __launch_bounds__(256, 1) void fuse_kernel(
    const float* __restrict__ Wp, const float* __restrict__ bp,
    const float* __restrict__ W1, const float* __restrict__ b1,
    float* __restrict__ ws)
{
    const int t = threadIdx.x;
    if (t < 96) {                      // Ma[d][k] = sum_f Wp[d][f] * W1[f][k]
        const int d = t >> 5, k = t & 31;
        float acc = 0.f;
#pragma unroll
        for (int f = 0; f < 16; ++f)
            acc = fmaf(Wp[d * 16 + f], W1[f * 32 + k], acc);
        ws[d * 32 + k] = acc;
    } else if (t < 192) {              // Mb[d][k] = sum_f Wp[d][f] * W1[16+f][k]
        const int u = t - 96;
        const int d = u >> 5, k = u & 31;
        float acc = 0.f;
#pragma unroll
        for (int f = 0; f < 16; ++f)
            acc = fmaf(Wp[d * 16 + f], W1[(16 + f) * 32 + k], acc);
        ws[96 + d * 32 + k] = acc;
    } else if (t < 224) {              // cc[k] = bp@(W1a+W1b) + b1
        const int k = t - 192;
        float acc = b1[k];
#pragma unroll
        for (int f = 0; f < 16; ++f)
            acc = fmaf(bp[f], W1[f * 32 + k] + W1[(16 + f) * 32 + k], acc);
        ws[192 + k] = acc;
    }
}

__global__ __launch_bounds__(256, 5) void gpn_kernel(
    const float* __restrict__ pos,  // (B,10,2)
    const float* __restrict__ ori,  // (B,10,1)
    const float* __restrict__ ws,   // Ma(96) ++ Mb(96) ++ cc(32)
    const float* __restrict__ W2,   // (32,8)
    const float* __restrict__ b2,   // (8)
    const float* __restrict__ W3,   // (8,2)
    const float* __restrict__ b3,   // (2)
    float* __restrict__ out,        // big_edge (B*100*2) ++ adjacency (B*100)
    int B)
{
    const int e = blockIdx.x * 256 + threadIdx.x;   // global edge id
    if (e >= B * 100) return;

    // ---- edge decode (compile-time-constant divisors -> mul_hi magic) ----
    const unsigned ue = (unsigned)e;
    const unsigned b  = ue / 100u;
    const unsigned rem = ue - b * 100u;
    const unsigned i  = rem / 10u;
    const unsigned c  = rem - i * 10u;
    const unsigned j  = (c == 0u) ? i : (((c - 1u) < i) ? (c - 1u) : c);

    // ---- node inputs (lanes of a wave share 1-2 graphs -> same cache lines) ----
    const v2f pi = ((const v2f*)pos)[b * 10u + i];
    const v2f pj = ((const v2f*)pos)[b * 10u + j];
    const float oi = ori[b * 10u + i];
    const float oj = ori[b * 10u + j];

    // ---- h1 = lrelu(cc + xi@Ma + xj@Mb): 6 fused FMAs per element ----
    const v4f* Ma = (const v4f*)ws;            // 24 v4f (3 rows x 8)
    const v4f* Mb = (const v4f*)(ws + 96);     // 24 v4f
    const v4f* cc = (const v4f*)(ws + 192);    // 8 v4f

    v4f h[8];
#pragma unroll
    for (int q = 0; q < 8; ++q) {
        v4f s = cc[q];
        s += pi.x * Ma[q];
        s += pi.y * Ma[8 + q];
        s += oi   * Ma[16 + q];
        s += pj.x * Mb[q];
        s += pj.y * Mb[8 + q];
        s += oj   * Mb[16 + q];
        h[q] = __builtin_elementwise_max(s, s * NEG);
    }

    // ---- layer 2: 32 -> 8 (8 independent accumulator chains) ----
    const v2f* w2p = (const v2f*)W2;           // row k: pairs [4k..4k+3]
    v2f a0 = ((const v2f*)b2)[0];
    v2f a1 = ((const v2f*)b2)[1];
    v2f a2 = ((const v2f*)b2)[2];
    v2f a3 = ((const v2f*)b2)[3];
#pragma unroll
    for (int q = 0; q < 8; ++q) {
        const v4f hh = h[q];
        const int k0 = 4 * q;
        a0 += hh.x * w2p[4 * (k0 + 0) + 0];
        a1 += hh.x * w2p[4 * (k0 + 0) + 1];
        a2 += hh.x * w2p[4 * (k0 + 0) + 2];
        a3 += hh.x * w2p[4 * (k0 + 0) + 3];
        a0 += hh.y * w2p[4 * (k0 + 1) + 0];
        a1 += hh.y * w2p[4 * (k0 + 1) + 1];
        a2 += hh.y * w2p[4 * (k0 + 1) + 2];
        a3 += hh.y * w2p[4 * (k0 + 1) + 3];
        a0 += hh.z * w2p[4 * (k0 + 2) + 0];
        a1 += hh.z * w2p[4 * (k0 + 2) + 1];
        a2 += hh.z * w2p[4 * (k0 + 2) + 2];
        a3 += hh.z * w2p[4 * (k0 + 2) + 3];
        a0 += hh.w * w2p[4 * (k0 + 3) + 0];
        a1 += hh.w * w2p[4 * (k0 + 3) + 1];
        a2 += hh.w * w2p[4 * (k0 + 3) + 2];
        a3 += hh.w * w2p[4 * (k0 + 3) + 3];
    }

    // ---- layer 3: lrelu then 8 -> 2 ----
    const v2f* w3p = (const v2f*)W3;
    const v2f h20 = __builtin_elementwise_max(a0, a0 * NEG);
    const v2f h21 = __builtin_elementwise_max(a1, a1 * NEG);
    const v2f h22 = __builtin_elementwise_max(a2, a2 * NEG);
    const v2f h23 = __builtin_elementwise_max(a3, a3 * NEG);

    v2f ev = ((const v2f*)b3)[0];
    ev += h20.x * w3p[0];
    ev += h20.y * w3p[1];
    ev += h21.x * w3p[2];
    ev += h21.y * w3p[3];
    ev += h22.x * w3p[4];
    ev += h22.y * w3p[5];
    ev += h23.x * w3p[6];
    ev += h23.y * w3p[7];

    // ---- stores: lane==edge -> wave writes 512B + 256B contiguous ----
    __builtin_nontemporal_store(ev, &((v2f*)out)[e]);
    const float av = (ev.y > ev.x) ? 1.0f : 0.0f;
    __builtin_nontemporal_store(av, &out[(size_t)B * 200 + e]);
}

extern "C" void kernel_launch(void* const* d_in, const int* in_sizes, int n_in,
                              void* d_out, int out_size, void* d_ws, size_t ws_size,
                              hipStream_t stream) {
    const float* pos = (const float*)d_in[0];
    const float* ori = (const float*)d_in[1];
    const float* Wp  = (const float*)d_in[2];
    const float* bp  = (const float*)d_in[3];
    const float* W1  = (const float*)d_in[4];
    const float* b1  = (const float*)d_in[5];
    const float* W2  = (const float*)d_in[6];
    const float* b2  = (const float*)d_in[7];
    const float* W3  = (const float*)d_in[8];
    const float* b3  = (const float*)d_in[9];
    float* out = (float*)d_out;
    float* ws  = (float*)d_ws;

    const int B = in_sizes[0] / 20;             // 16384
    const int nEdges = B * 100;                 // 1,638,400
    const int nBlocks = (nEdges + 255) / 256;   // 6400

    fuse_kernel<<<1, 256, 0, stream>>>(Wp, bp, W1, b1, ws);
    gpn_kernel<<<nBlocks, 256, 0, stream>>>(pos, ori, ws, W2, b2, W3, b3, out, B);
}

// Round 11
// 92.632 us; speedup vs baseline: 1.0394x; 1.0394x over previous
//
#include <hip/hip_runtime.h>

// GraphProposalNetwork on MI355X — final (restore of round-9 best: 94.26 µs).
// Algebra: feat=x@Wp+bp is linear into W1 and pair=[vi,vj], so
//   h1[b,i,j,:] = lrelu( g_a[b,i,:] + g_b[b,j,:] ) with per-node g = x@(Wp@W1half)+bias.
// Single kernel; per-block fuse of M=Wp@[W1a|W1b]+bias (overlapped across all
// blocks, no serial pre-dispatch); lane=(graph,i) row with a-half in registers;
// j-natural LDS reads (0 bank conflicts, verified R7); K-sliced SGPR-resident
// W2; results staged in LDS and written as coalesced full-line NT stores.
// Session evidence: bench time 94-96 µs invariant across radically different
// kernel structures -> timed window dominated by harness poison-fills (~42 µs
// for 268 MB ws fill) + fixed replay overhead; kernel is near its ~5 µs floor.

typedef float v2f __attribute__((ext_vector_type(2)));
typedef float v4f __attribute__((ext_vector_type(4)));

constexpr int G = 24;            // graphs per block (240 of 256 lanes active)
constexpr int GB_STRIDE = 36;    // floats per gb row: 32 + 4 pad (16B aligned)
constexpr float NEG = 0.2f;

constexpr int SGB_FLOATS = G * 10 * GB_STRIDE;   // 8640; epilogue overlays 7200
constexpr int RES_E_FLOATS = G * 200;            // 4800

__global__ __launch_bounds__(256, 2) void gpn_kernel(
    const float* __restrict__ pos,  // (B,10,2)
    const float* __restrict__ ori,  // (B,10,1)
    const float* __restrict__ Wp,   // (3,16)
    const float* __restrict__ bp,   // (16)
    const float* __restrict__ W1,   // (32,32)
    const float* __restrict__ b1,   // (32)
    const float* __restrict__ W2,   // (32,8)
    const float* __restrict__ b2,   // (8)
    const float* __restrict__ W3,   // (8,2)
    const float* __restrict__ b3,   // (2)
    float* __restrict__ out,        // big_edge (B*100*2) ++ adjacency (B*100)
    int B)
{
    __shared__ float sL[SGB_FLOATS];   // gb rows; later overlaid with results
    __shared__ float sM[3 * 64];       // fused Wp@[W1a|W1b]
    __shared__ float sc[64];           // fused bias (b1 folded into first 32)

    const int t = threadIdx.x;
    const int bBase = blockIdx.x * G;
    const int remG0 = B - bBase;
    const int remG = (remG0 < G) ? remG0 : G;
    const int nRows = remG * 10;

    const int r = t;
    const int g = r / 10;
    const int i = r - g * 10;

    // ---- issue this lane's node loads FIRST (latency overlaps phase A) ----
    v2f p = {0.f, 0.f};
    float o = 0.f;
    if (r < nRows) {
        const int node = bBase * 10 + r;
        p = ((const v2f*)pos)[node];
        o = ori[node];
    }

    // ---- Phase A (per-block): M = Wp@[W1a|W1b] (3x64), c = bp@[.] (+b1) ----
    if (t < 192) {
        const int d = t >> 6, k = t & 63;
        const int kk = k & 31;
        const int fo = (k < 32) ? 0 : 16;
        float acc = 0.f;
#pragma unroll
        for (int f = 0; f < 16; ++f)
            acc = fmaf(Wp[d * 16 + f], W1[(fo + f) * 32 + kk], acc);
        sM[d * 64 + k] = acc;
    } else {
        const int k = t - 192;
        const int kk = k & 31;
        const int fo = (k < 32) ? 0 : 16;
        float acc = 0.f;
#pragma unroll
        for (int f = 0; f < 16; ++f)
            acc = fmaf(bp[f], W1[(fo + f) * 32 + kk], acc);
        if (k < 32) acc += b1[k];
        sc[k] = acc;
    }
    __syncthreads();

    // ---- Phase B: lane owns row r=(g,i); a-half (k<32) in registers,
    // b-half (k>=32) to LDS. sM/sc reads are same-address broadcast. ----
    v4f ga[8];
    if (r < nRows) {
        const v4f* m4 = (const v4f*)sM;   // 48 v4f
        const v4f* c4 = (const v4f*)sc;   // 16 v4f
        v4f* dst = (v4f*)&sL[r * GB_STRIDE];
#pragma unroll
        for (int q = 0; q < 8; ++q) {
            v4f gg = c4[q];
            gg += p.x * m4[q];
            gg += p.y * m4[16 + q];
            gg += o   * m4[32 + q];
            ga[q] = gg;
        }
#pragma unroll
        for (int q = 8; q < 16; ++q) {
            v4f gg = c4[q];
            gg += p.x * m4[q];
            gg += p.y * m4[16 + q];
            gg += o   * m4[32 + q];
            dst[q - 8] = gg;
        }
    }
    __syncthreads();

    // ---- Phase C: K-sliced layer 2, j in natural order (wave-broadcast LDS
    // reads, zero bank conflicts — verified R7). W2 via wave-uniform s_load. ----
    v2f A[10][4];
    if (r < nRows) {
        const v2f* w2p = (const v2f*)W2;
        const v2f bb2_0 = ((const v2f*)b2)[0];
        const v2f bb2_1 = ((const v2f*)b2)[1];
        const v2f bb2_2 = ((const v2f*)b2)[2];
        const v2f bb2_3 = ((const v2f*)b2)[3];

        const float* gbase = &sL[(g * 10) * GB_STRIDE];

#pragma unroll
        for (int j = 0; j < 10; ++j) {
            A[j][0] = bb2_0; A[j][1] = bb2_1; A[j][2] = bb2_2; A[j][3] = bb2_3;
        }

#pragma unroll
        for (int q = 0; q < 8; ++q) {
            const v4f gaq = ga[q];
            const int k0 = 4 * q;
            const v2f w00 = w2p[4 * (k0 + 0) + 0], w01 = w2p[4 * (k0 + 0) + 1],
                      w02 = w2p[4 * (k0 + 0) + 2], w03 = w2p[4 * (k0 + 0) + 3];
            const v2f w10 = w2p[4 * (k0 + 1) + 0], w11 = w2p[4 * (k0 + 1) + 1],
                      w12 = w2p[4 * (k0 + 1) + 2], w13 = w2p[4 * (k0 + 1) + 3];
            const v2f w20 = w2p[4 * (k0 + 2) + 0], w21 = w2p[4 * (k0 + 2) + 1],
                      w22 = w2p[4 * (k0 + 2) + 2], w23 = w2p[4 * (k0 + 2) + 3];
            const v2f w30 = w2p[4 * (k0 + 3) + 0], w31 = w2p[4 * (k0 + 3) + 1],
                      w32 = w2p[4 * (k0 + 3) + 2], w33 = w2p[4 * (k0 + 3) + 3];
#pragma unroll
            for (int j = 0; j < 10; ++j) {
                const v4f gb = *(const v4f*)(gbase + j * GB_STRIDE + 4 * q);
                const v4f s = gaq + gb;
                const v4f h = __builtin_elementwise_max(s, s * NEG);
                A[j][0] += h.x * w00; A[j][1] += h.x * w01;
                A[j][2] += h.x * w02; A[j][3] += h.x * w03;
                A[j][0] += h.y * w10; A[j][1] += h.y * w11;
                A[j][2] += h.y * w12; A[j][3] += h.y * w13;
                A[j][0] += h.z * w20; A[j][1] += h.z * w21;
                A[j][2] += h.z * w22; A[j][3] += h.z * w23;
                A[j][0] += h.w * w30; A[j][1] += h.w * w31;
                A[j][2] += h.w * w32; A[j][3] += h.w * w33;
            }
        }
    }
    __syncthreads();   // all sL reads done; safe to overlay results

    // ---- layer 3; results into LDS at permuted column c(j) ----
    float* res_e = sL;                    // [G*200] big_edge, block-flat
    float* res_a = sL + RES_E_FLOATS;     // [G*100] adjacency
    if (r < nRows) {
        const v2f* w3p = (const v2f*)W3;
        const v2f bb3 = ((const v2f*)b3)[0];
#pragma unroll
        for (int j = 0; j < 10; ++j) {
            const v2f h20 = __builtin_elementwise_max(A[j][0], A[j][0] * NEG);
            const v2f h21 = __builtin_elementwise_max(A[j][1], A[j][1] * NEG);
            const v2f h22 = __builtin_elementwise_max(A[j][2], A[j][2] * NEG);
            const v2f h23 = __builtin_elementwise_max(A[j][3], A[j][3] * NEG);

            v2f ev = bb3;
            ev += h20.x * w3p[0];
            ev += h20.y * w3p[1];
            ev += h21.x * w3p[2];
            ev += h21.y * w3p[3];
            ev += h22.x * w3p[4];
            ev += h22.y * w3p[5];
            ev += h23.x * w3p[6];
            ev += h23.y * w3p[7];

            const int c = (j == i) ? 0 : ((j < i) ? (j + 1) : j);
            const int eIdx = r * 10 + c;            // (g*10+i)*10+c
            *(v2f*)&res_e[eIdx * 2] = ev;           // ds_write_b64
            res_a[eIdx] = (ev.y > ev.x) ? 1.0f : 0.0f;
        }
    }
    __syncthreads();

    // ---- coalesced full-line non-temporal stores ----
    {
        const int nV4e = remG * 50;                 // big_edge v4f count
        const v4f* se = (const v4f*)res_e;
        v4f* oe = (v4f*)(out + (size_t)bBase * 200);
        for (int idx = t; idx < nV4e; idx += 256)
            __builtin_nontemporal_store(se[idx], &oe[idx]);

        const int nV4a = remG * 25;                 // adjacency v4f count
        const v4f* sa = (const v4f*)res_a;
        v4f* oa = (v4f*)(out + (size_t)B * 200 + (size_t)bBase * 100);
        for (int idx = t; idx < nV4a; idx += 256)
            __builtin_nontemporal_store(sa[idx], &oa[idx]);
    }
}

extern "C" void kernel_launch(void* const* d_in, const int* in_sizes, int n_in,
                              void* d_out, int out_size, void* d_ws, size_t ws_size,
                              hipStream_t stream) {
    const float* pos = (const float*)d_in[0];
    const float* ori = (const float*)d_in[1];
    const float* Wp  = (const float*)d_in[2];
    const float* bp  = (const float*)d_in[3];
    const float* W1  = (const float*)d_in[4];
    const float* b1  = (const float*)d_in[5];
    const float* W2  = (const float*)d_in[6];
    const float* b2  = (const float*)d_in[7];
    const float* W3  = (const float*)d_in[8];
    const float* b3  = (const float*)d_in[9];
    float* out = (float*)d_out;

    const int B = in_sizes[0] / 20;           // 16384
    const int nBlocks = (B + G - 1) / G;      // 683

    gpn_kernel<<<nBlocks, 256, 0, stream>>>(pos, ori, Wp, bp, W1, b1, W2, b2,
                                            W3, b3, out, B);
}